// Round 6
// baseline (592.788 us; speedup 1.0000x reference)
//
#include <hip/hip_runtime.h>
#include <hip/hip_bf16.h>

// ---------------------------------------------------------------------------
// MultiheadAttention (B=4, S=8192, E=1024, H=16, D=64) — bf16 MFMA.
// R12: fused mega-kernel with SOFTWARE grid barrier (plain launch).
// R11's hipLaunchCooperativeKernel failed under the harness's graph capture
// (output ~ zeros -> launch never recorded). Same 5 phases, same bodies
// (R7/R8-verified), but grid sync = sense-reversing device-scope atomic
// barrier in d_ws, zeroed via hipMemsetAsync before the kernel (both nodes
// capture into the graph). Deadlock-safe: grid 512 blocks; LDS 48 KB +
// launch_bounds(256,2) (VGPR<=256) => >=2 blocks/CU * 256 CU = capacity
// >= 512 => all blocks co-resident.
//   phase0 convw (grid-strided)
//   phase1 qkv_gemm (R8 body: 2:1 wave tiling, counted VMWAIT(14) dbuf)
//   phase2 vtrans
//   phase3 attn_flash (counted VMWAIT(4) dbuf)
//   phase4 gemm_o     (counted VMWAIT(4) dbuf)
// Purpose: (a) kill 4 launch gaps; (b) one dispatch > 77 µs fill cutoff ->
// direct GPU-time readout in rocprof top-5 for every future round.
//
// MFMA 16x16x32 bf16 layouts (m89/m91-verified):
//   A frag: lane q*16+r holds A[m=r][k=q*8+j]
//   B frag: lane q*16+r holds B[n=r][k=q*8+j]
//   C/D   : lane q*16+r holds D[row=q*4+e][col=r]
// ---------------------------------------------------------------------------

typedef unsigned short u16;
typedef __attribute__((ext_vector_type(8))) short short8;
typedef __attribute__((ext_vector_type(4))) float f32x4;

#define VMWAIT(N) asm volatile("s_waitcnt vmcnt(" #N ")" ::: "memory")
#define MEMFENCE() asm volatile("" ::: "memory")
#define BAR() __builtin_amdgcn_s_barrier()

__device__ inline u16 f2bf(float f) {
    union { float f; unsigned u; } v; v.f = f;
    unsigned u = v.u;
    return (u16)((u + 0x7fffu + ((u >> 16) & 1u)) >> 16);  // RNE
}
__device__ inline unsigned pack_bf2(float a, float b) {
    union { __hip_bfloat162 h; unsigned u; } v;
    v.h = __float22bfloat162_rn(float2{a, b});
    return v.u;
}
// Async global->LDS, 16 B per lane. LDS dest = wave-uniform base + lane*16.
__device__ __forceinline__ void gld16(void* lds, const void* gptr) {
    __builtin_amdgcn_global_load_lds(
        (const __attribute__((address_space(1))) unsigned int*)gptr,
        (__attribute__((address_space(3))) unsigned int*)lds,
        16, 0, 0);
}

// Sense-reversing software grid barrier (device-scope atomics).
// Safe because all NBLK blocks are co-resident (see header comment).
__device__ __forceinline__ void gbar(unsigned* cnt, unsigned* gen, unsigned nblk) {
    __syncthreads();
    if (threadIdx.x == 0) {
        __threadfence();   // flush this block's global writes device-wide
        // per-location coherence: this thread's prior acquire of gen makes
        // this relaxed read >= the generation it last observed.
        unsigned g = __hip_atomic_load(gen, __ATOMIC_RELAXED,
                                       __HIP_MEMORY_SCOPE_AGENT);
        unsigned a = __hip_atomic_fetch_add(cnt, 1u, __ATOMIC_ACQ_REL,
                                            __HIP_MEMORY_SCOPE_AGENT);
        if (a + 1u == nblk) {
            __hip_atomic_store(cnt, 0u, __ATOMIC_RELAXED,
                               __HIP_MEMORY_SCOPE_AGENT);
            __hip_atomic_store(gen, g + 1u, __ATOMIC_RELEASE,
                               __HIP_MEMORY_SCOPE_AGENT);
        } else {
            while (__hip_atomic_load(gen, __ATOMIC_ACQUIRE,
                                     __HIP_MEMORY_SCOPE_AGENT) == g)
                __builtin_amdgcn_s_sleep(1);
        }
        __threadfence();
    }
    __syncthreads();
}

// ---------------------------------------------------------------------------
__global__ __launch_bounds__(256, 2) void mha_fused(
    const float* __restrict__ X,
    const float* __restrict__ Wq, const float* __restrict__ bq,
    const float* __restrict__ Wk, const float* __restrict__ bk,
    const float* __restrict__ Wv, const float* __restrict__ bv,
    const float* __restrict__ Wo, const float* __restrict__ bo,
    float* __restrict__ out,
    u16* __restrict__ qkv, u16* __restrict__ Vt, u16* __restrict__ Wqkv,
    u16* __restrict__ Wob, float* __restrict__ qkvb, u16* __restrict__ ctx,
    unsigned* __restrict__ bar)
{
    __shared__ __align__(16) char smraw[49152];   // union across phases

    unsigned* bcnt = bar;
    unsigned* bgen = bar + 1;

    const int tid = threadIdx.x;
    const int bid = blockIdx.x;                   // 0..511
    const int lane = tid & 63, wid = tid >> 6;    // 4 waves
    const int q = lane >> 4, r = lane & 15;

    // =====================================================================
    // phase 0: convw  (virtual 4096 blocks, grid-stride)
    // =====================================================================
    for (int vb = bid; vb < 4096; vb += 512) {
        const int idx = vb * 256 + tid;           // 0 .. 1048575
        Wob[idx] = f2bf(Wo[idx]);
        if (idx < 196608) {
            const int row = idx >> 10, k = idx & 1023;
            float v = (row < 64)  ? Wq[row * 1024 + k] * 0.125f
                    : (row < 128) ? Wk[(row - 64) * 1024 + k]
                                  : Wv[(row - 128) * 1024 + k];
            Wqkv[idx] = f2bf(v);
        }
        if (idx < 192) {
            qkvb[idx] = (idx < 64) ? bq[idx] * 0.125f
                      : (idx < 128) ? bk[idx - 64] : bv[idx - 128];
        }
    }
    gbar(bcnt, bgen, 512);

    // =====================================================================
    // phase 1: qkv_gemm — qkv[32768][192] = bf16(X) @ Wqkv^T + b
    // (R8 body: wave(wm,wn) = 32 rows x 96 cols, counted VMWAIT(14) dbuf)
    // =====================================================================
    {
        short8 (*Bs)[1536] = reinterpret_cast<short8 (*)[1536]>(smraw);
        const int wm = wid >> 1, wn = wid & 1;
        const long m0 = (long)bid * 64;

        const u16* wp[6];
        #pragma unroll
        for (int i = 0; i < 6; ++i) {
            const int p = wid * 6 + i, kk2 = p / 12, nt = p % 12;
            wp[i] = Wqkv + (long)(nt * 16 + r) * 1024 + kk2 * 32 + q * 8;
        }
        const float* px0 = X + (m0 + wm * 32 + r) * 1024 + q * 8;
        const float* px1 = px0 + 16 * 1024;

        f32x4 acc[2][6] = {};
        float4 a[2][4];
        a[0][0] = *(const float4*)(px0);
        a[0][1] = *(const float4*)(px0 + 4);
        a[0][2] = *(const float4*)(px0 + 32);
        a[0][3] = *(const float4*)(px0 + 36);
        a[1][0] = *(const float4*)(px1);
        a[1][1] = *(const float4*)(px1 + 4);
        a[1][2] = *(const float4*)(px1 + 32);
        a[1][3] = *(const float4*)(px1 + 36);
        MEMFENCE();
        #pragma unroll
        for (int i = 0; i < 6; ++i)
            gld16(&Bs[0][(wid * 6 + i) * 64], wp[i]);

        for (int k0 = 0; k0 < 1024; k0 += 64) {
            const int buf = (k0 >> 6) & 1;
            float4 an[2][4];
            if (k0 + 64 < 1024) {
                an[0][0] = *(const float4*)(px0 + k0 + 64);
                an[0][1] = *(const float4*)(px0 + k0 + 68);
                an[0][2] = *(const float4*)(px0 + k0 + 96);
                an[0][3] = *(const float4*)(px0 + k0 + 100);
                an[1][0] = *(const float4*)(px1 + k0 + 64);
                an[1][1] = *(const float4*)(px1 + k0 + 68);
                an[1][2] = *(const float4*)(px1 + k0 + 96);
                an[1][3] = *(const float4*)(px1 + k0 + 100);
                MEMFENCE();
                #pragma unroll
                for (int i = 0; i < 6; ++i)
                    gld16(&Bs[buf ^ 1][(wid * 6 + i) * 64], wp[i] + k0 + 64);
                VMWAIT(14);
            } else {
                VMWAIT(0);
            }
            BAR();
            MEMFENCE();
            #pragma unroll
            for (int kk2 = 0; kk2 < 2; ++kk2) {
                union { short8 s; unsigned u[4]; } af0, af1;
                af0.u[0] = pack_bf2(a[0][kk2 * 2].x, a[0][kk2 * 2].y);
                af0.u[1] = pack_bf2(a[0][kk2 * 2].z, a[0][kk2 * 2].w);
                af0.u[2] = pack_bf2(a[0][kk2 * 2 + 1].x, a[0][kk2 * 2 + 1].y);
                af0.u[3] = pack_bf2(a[0][kk2 * 2 + 1].z, a[0][kk2 * 2 + 1].w);
                af1.u[0] = pack_bf2(a[1][kk2 * 2].x, a[1][kk2 * 2].y);
                af1.u[1] = pack_bf2(a[1][kk2 * 2].z, a[1][kk2 * 2].w);
                af1.u[2] = pack_bf2(a[1][kk2 * 2 + 1].x, a[1][kk2 * 2 + 1].y);
                af1.u[3] = pack_bf2(a[1][kk2 * 2 + 1].z, a[1][kk2 * 2 + 1].w);
                #pragma unroll
                for (int j = 0; j < 6; ++j) {
                    const short8 bf = Bs[buf][(kk2 * 12 + wn * 6 + j) * 64 + lane];
                    acc[0][j] = __builtin_amdgcn_mfma_f32_16x16x32_bf16(
                        af0.s, bf, acc[0][j], 0, 0, 0);
                    acc[1][j] = __builtin_amdgcn_mfma_f32_16x16x32_bf16(
                        af1.s, bf, acc[1][j], 0, 0, 0);
                }
            }
            MEMFENCE();
            BAR();
            if (k0 + 64 < 1024) {
                #pragma unroll
                for (int mf = 0; mf < 2; ++mf)
                    #pragma unroll
                    for (int i = 0; i < 4; ++i) a[mf][i] = an[mf][i];
            }
        }

        // epilogue: repack via LDS -> contiguous 16B/lane stores
        u16* lds0 = (u16*)&Bs[0][0];
        #pragma unroll
        for (int j = 0; j < 6; ++j) {
            const int col = wn * 96 + j * 16 + r;
            const float badd = qkvb[col];
            #pragma unroll
            for (int mf = 0; mf < 2; ++mf)
                #pragma unroll
                for (int e = 0; e < 4; ++e)
                    lds0[(wm * 32 + mf * 16 + q * 4 + e) * 192 + col] =
                        f2bf(acc[mf][j][e] + badd);
        }
        asm volatile("s_waitcnt lgkmcnt(0)" ::: "memory");
        BAR();
        const short8* l8 = (const short8*)lds0;
        u16* ob = qkv + m0 * 192;
        #pragma unroll
        for (int s = 0; s < 6; ++s) {
            short8 v = l8[tid + s * 256];
            *(short8*)(ob + (long)(tid + s * 256) * 8) = v;
        }
    }
    gbar(bcnt, bgen, 512);

    // =====================================================================
    // phase 2: vtrans — Vt[bh*64+d][i] <- qkv[b*8192 + i*16 + h][128+d]
    // (virtual grid dim3(64,8): bh = bid&63, i0 = (bid>>6)*64)
    // =====================================================================
    {
        u16 (*T)[68] = reinterpret_cast<u16 (*)[68]>(smraw);
        const int bh = bid & 63, b = bh >> 4, h = bh & 15;
        const int i0 = (bid >> 6) * 64;

        #pragma unroll
        for (int it = 0; it < 2; ++it) {
            const int c = tid + 256 * it;
            const int il = c >> 3, d8 = (c & 7) * 8;
            short8 v = *(const short8*)(qkv +
                ((long)b * 8192 + (long)(i0 + il) * 16 + h) * 192 + 128 + d8);
            #pragma unroll
            for (int j = 0; j < 8; ++j) T[d8 + j][il] = (u16)v[j];
        }
        __syncthreads();
        #pragma unroll
        for (int it = 0; it < 2; ++it) {
            const int c = tid + 256 * it;
            const int dl = c >> 3, i8 = (c & 7) * 8;
            short8 o;
            #pragma unroll
            for (int j = 0; j < 8; ++j) o[j] = (short)T[dl][i8 + j];
            *(short8*)(Vt + ((long)bh * 64 + dl) * 512 + i0 + i8) = o;
        }
    }
    gbar(bcnt, bgen, 512);

    // =====================================================================
    // phase 3: attn_flash — ctx = softmax(Qh Kh^T) Vh   (S^T formulation)
    // (virtual grid dim3(8,64): qt = bid&7, bh = bid>>3)
    // =====================================================================
    {
        short8 (*Ks)[512] = reinterpret_cast<short8 (*)[512]>(smraw);
        short8 (*Vs)[512] = reinterpret_cast<short8 (*)[512]>(smraw + 16384);
        u16* Plds = reinterpret_cast<u16*>(smraw + 32768);   // [4][16*72]

        const int qt = bid & 7, bh = bid >> 3;
        const int b = bh >> 4, h = bh & 15;
        const long qrowbase = (long)b * 8192 + h;

        short8 Qf0, Qf1;
        {
            const int i = qt * 64 + wid * 16 + r;
            const u16* p = qkv + (qrowbase + (long)i * 16) * 192 + q * 8;
            Qf0 = *(const short8*)(p);
            Qf1 = *(const short8*)(p + 32);
        }

        const u16* kbase = qkv + (qrowbase + (long)(wid * 16 + r) * 16) * 192
                               + 64 + q * 8;
        const u16* vbase = Vt + ((long)bh * 64 + wid * 16 + r) * 512 + q * 8;

        gld16(&Ks[0][wid * 64],       kbase);
        gld16(&Ks[0][256 + wid * 64], kbase + 32);
        gld16(&Vs[0][wid * 64],       vbase);
        gld16(&Vs[0][256 + wid * 64], vbase + 32);

        f32x4 O[4] = {};
        float mrun = -1e30f, lrun = 0.f;
        u16* Pw = Plds + wid * 1152;

        for (int c = 0; c < 8; ++c) {
            const int j0 = c * 64, buf = c & 1;
            if (c < 7) {
                const u16* kp = kbase + (long)(j0 + 64) * 3072;
                const u16* vp = vbase + j0 + 64;
                gld16(&Ks[buf ^ 1][wid * 64],       kp);
                gld16(&Ks[buf ^ 1][256 + wid * 64], kp + 32);
                gld16(&Vs[buf ^ 1][wid * 64],       vp);
                gld16(&Vs[buf ^ 1][256 + wid * 64], vp + 32);
                VMWAIT(4);
            } else {
                VMWAIT(0);
            }
            BAR();
            MEMFENCE();
            f32x4 S[4];
            #pragma unroll
            for (int ct = 0; ct < 4; ++ct) {
                f32x4 s = {};
                s = __builtin_amdgcn_mfma_f32_16x16x32_bf16(
                    Ks[buf][ct * 64 + lane], Qf0, s, 0, 0, 0);
                s = __builtin_amdgcn_mfma_f32_16x16x32_bf16(
                    Ks[buf][256 + ct * 64 + lane], Qf1, s, 0, 0, 0);
                S[ct] = s;
            }
            float mc = -1e30f;
            #pragma unroll
            for (int ct = 0; ct < 4; ++ct)
                mc = fmaxf(mc, fmaxf(fmaxf(S[ct][0], S[ct][1]),
                                     fmaxf(S[ct][2], S[ct][3])));
            mc = fmaxf(mc, __shfl_xor(mc, 16, 64));
            mc = fmaxf(mc, __shfl_xor(mc, 32, 64));
            const float mnew = fmaxf(mrun, mc);
            const float alpha = __expf(mrun - mnew);
            mrun = mnew;
            float se = 0.f;
            #pragma unroll
            for (int ct = 0; ct < 4; ++ct)
                #pragma unroll
                for (int e = 0; e < 4; ++e) {
                    const float pv = __expf(S[ct][e] - mnew);
                    S[ct][e] = pv; se += pv;
                }
            se += __shfl_xor(se, 16, 64);
            se += __shfl_xor(se, 32, 64);
            lrun = lrun * alpha + se;
            #pragma unroll
            for (int nt = 0; nt < 4; ++nt)
                #pragma unroll
                for (int e = 0; e < 4; ++e) O[nt][e] *= alpha;
            #pragma unroll
            for (int ct = 0; ct < 4; ++ct) {
                uint2 d;
                d.x = pack_bf2(S[ct][0], S[ct][1]);
                d.y = pack_bf2(S[ct][2], S[ct][3]);
                *(uint2*)(Pw + r * 72 + ct * 16 + q * 4) = d;
            }
            short8 Pf0 = *(const short8*)(Pw + r * 72 + q * 8);
            short8 Pf1 = *(const short8*)(Pw + r * 72 + 32 + q * 8);
            #pragma unroll
            for (int nt = 0; nt < 4; ++nt) {
                O[nt] = __builtin_amdgcn_mfma_f32_16x16x32_bf16(
                    Vs[buf][nt * 64 + lane], Pf0, O[nt], 0, 0, 0);
                O[nt] = __builtin_amdgcn_mfma_f32_16x16x32_bf16(
                    Vs[buf][256 + nt * 64 + lane], Pf1, O[nt], 0, 0, 0);
            }
            MEMFENCE();
            BAR();
        }

        const float inv = 1.0f / lrun;
        const long i = qt * 64 + wid * 16 + r;
        u16* po = ctx + ((long)b * 512 + i) * 1024 + h * 64;
        #pragma unroll
        for (int nt = 0; nt < 4; ++nt) {
            uint2 d;
            d.x = pack_bf2(O[nt][0] * inv, O[nt][1] * inv);
            d.y = pack_bf2(O[nt][2] * inv, O[nt][3] * inv);
            *(uint2*)(po + nt * 16 + q * 4) = d;
        }
    }
    gbar(bcnt, bgen, 512);

    // =====================================================================
    // phase 4: gemm_o — out[2048][1024] fp32 = ctx @ Wob^T + bo
    // (virtual grid dim3(32,16): m0 = (bid&31)*64, n0 = (bid>>5)*64)
    // =====================================================================
    {
        short8 (*As)[512]  = reinterpret_cast<short8 (*)[512]>(smraw);
        short8 (*Bs2)[512] = reinterpret_cast<short8 (*)[512]>(smraw + 16384);

        const long m0 = (long)(bid & 31) * 64, n0 = (long)(bid >> 5) * 64;
        const int wm = wid >> 1, wn = wid & 1;

        const u16* ap[2];
        const u16* bp[2];
        #pragma unroll
        for (int i = 0; i < 2; ++i) {
            const int t = wid * 2 + i, f = t >> 2, mt = t & 3;
            ap[i] = ctx + (m0 + mt * 16 + r) * 1024 + f * 32 + q * 8;
            bp[i] = Wob + (n0 + mt * 16 + r) * 1024 + f * 32 + q * 8;
        }

        #pragma unroll
        for (int i = 0; i < 2; ++i) {
            gld16(&As[0][(wid * 2 + i) * 64], ap[i]);
            gld16(&Bs2[0][(wid * 2 + i) * 64], bp[i]);
        }

        f32x4 acc[2][2] = {};

        for (int k0 = 0; k0 < 1024; k0 += 64) {
            const int buf = (k0 >> 6) & 1;
            if (k0 + 64 < 1024) {
                #pragma unroll
                for (int i = 0; i < 2; ++i) {
                    gld16(&As[buf ^ 1][(wid * 2 + i) * 64], ap[i] + k0 + 64);
                    gld16(&Bs2[buf ^ 1][(wid * 2 + i) * 64], bp[i] + k0 + 64);
                }
                VMWAIT(4);
            } else {
                VMWAIT(0);
            }
            BAR();
            MEMFENCE();
            #pragma unroll
            for (int f = 0; f < 2; ++f) {
                short8 af0 = As[buf][f * 256 + (wm * 2 + 0) * 64 + lane];
                short8 af1 = As[buf][f * 256 + (wm * 2 + 1) * 64 + lane];
                short8 bf0 = Bs2[buf][f * 256 + (wn * 2 + 0) * 64 + lane];
                short8 bf1 = Bs2[buf][f * 256 + (wn * 2 + 1) * 64 + lane];
                acc[0][0] = __builtin_amdgcn_mfma_f32_16x16x32_bf16(af0, bf0, acc[0][0], 0, 0, 0);
                acc[0][1] = __builtin_amdgcn_mfma_f32_16x16x32_bf16(af0, bf1, acc[0][1], 0, 0, 0);
                acc[1][0] = __builtin_amdgcn_mfma_f32_16x16x32_bf16(af1, bf0, acc[1][0], 0, 0, 0);
                acc[1][1] = __builtin_amdgcn_mfma_f32_16x16x32_bf16(af1, bf1, acc[1][1], 0, 0, 0);
            }
            MEMFENCE();
            BAR();
        }

        #pragma unroll
        for (int i = 0; i < 2; ++i)
            #pragma unroll
            for (int j = 0; j < 2; ++j) {
                const long col = n0 + (wn * 2 + j) * 16 + r;
                const float badd = bo[col];
                #pragma unroll
                for (int e = 0; e < 4; ++e) {
                    const long row = m0 + (wm * 2 + i) * 16 + q * 4 + e;
                    out[row * 1024 + col] = acc[i][j][e] + badd;
                }
            }
    }
}

// ---------------------------------------------------------------------------
extern "C" void kernel_launch(void* const* d_in, const int* in_sizes, int n_in,
                              void* d_out, int out_size, void* d_ws, size_t ws_size,
                              hipStream_t stream)
{
    const float* x  = (const float*)d_in[0];
    const float* Wq = (const float*)d_in[1];
    const float* bq = (const float*)d_in[2];
    const float* Wk = (const float*)d_in[3];
    const float* bk = (const float*)d_in[4];
    const float* Wv = (const float*)d_in[5];
    const float* bv = (const float*)d_in[6];
    const float* Wo = (const float*)d_in[7];
    const float* bo = (const float*)d_in[8];
    float* out = (float*)d_out;
    char* ws = (char*)d_ws;

    u16*     qkv  = (u16*)(ws);                 // 32768*192*2   = 12,582,912
    u16*     Vt   = (u16*)(ws + 12582912);      // 64*64*512*2   =  4,194,304
    u16*     Wqkv = (u16*)(ws + 16777216);      // 192*1024*2    =    393,216
    u16*     Wob  = (u16*)(ws + 17170432);      // 1024*1024*2   =  2,097,152
    float*   qkvb = (float*)(ws + 19267584);    // 192*4
    u16*     ctx  = (u16*)(ws + 19268352);      // 2048*1024*2   =  4,194,304
    unsigned* bar = (unsigned*)(ws + 25165824); // 2 words (cnt, gen)

    // zero the barrier words (capturable memset node, ordered before kernel)
    hipMemsetAsync(bar, 0, 16, stream);

    mha_fused<<<512, 256, 0, stream>>>(
        x, Wq, bq, Wk, bk, Wv, bv, Wo, bo, out,
        qkv, Vt, Wqkv, Wob, qkvb, ctx, bar);
}

// Round 7
// 262.570 us; speedup vs baseline: 2.2576x; 2.2576x over previous
//
#include <hip/hip_runtime.h>
#include <hip/hip_bf16.h>

// ---------------------------------------------------------------------------
// MultiheadAttention (B=4, S=8192, E=1024, H=16, D=64) — bf16 MFMA.
// R13: back to 5 kernels (R12 proved software grid barriers cost ~70 µs each
// — fusion strictly worse). qkv_gemm rebuilt on the ingest-bandwidth theory:
// R8's 79 µs = 1792 KB issued per CU / 10 B/cyc/CU vector-memory ceiling
// (A-loads duplicated across the wn wave pair + W re-read by every block;
// schedule changes R7-R10 never changed traffic -> all null).
// New qkv: 256 blocks x 512 thr, tile 128x192. A staged ONCE into LDS
// (coalesced gld16, XOR-swizzled global source, swizzled ds_read — rule 21
// both-sides pattern), W amortized over 2x rows. Per-CU issued bytes
// 1792 KB -> 896 KB. Counted VMWAIT(7), two barriers/step.
// attn_flash / gemm_o / vtrans / convw: R7-verified bodies, untouched.
//
//   qkv = x @ [Wq*0.125 | Wk | Wv]^T + [bq*0.125 | bk | bv]   (bf16, 32768x192)
//   Qh[b,h,i,d] = qkv[b*8192 + i*16 + h][d]      (S' = 512)
//   fused: ctx[b*512+i][h*64+d] = softmax(Qh Kh^T) @ Vh   (no score buffer)
//   out = ctx @ Wo^T + bo (fp32)
//
// MFMA 16x16x32 bf16 layouts (m89/m91-verified):
//   A frag: lane q*16+r holds A[m=r][k=q*8+j]
//   B frag: lane q*16+r holds B[n=r][k=q*8+j]
//   C/D   : lane q*16+r holds D[row=q*4+e][col=r]
// ---------------------------------------------------------------------------

typedef unsigned short u16;
typedef __attribute__((ext_vector_type(8))) short short8;
typedef __attribute__((ext_vector_type(4))) float f32x4;

#define VMWAIT(N) asm volatile("s_waitcnt vmcnt(" #N ")" ::: "memory")
#define MEMFENCE() asm volatile("" ::: "memory")
#define BAR() __builtin_amdgcn_s_barrier()

__device__ inline u16 f2bf(float f) {
    union { float f; unsigned u; } v; v.f = f;
    unsigned u = v.u;
    return (u16)((u + 0x7fffu + ((u >> 16) & 1u)) >> 16);  // RNE
}
__device__ inline unsigned pack_bf2(float a, float b) {
    union { __hip_bfloat162 h; unsigned u; } v;
    v.h = __float22bfloat162_rn(float2{a, b});
    return v.u;
}
// Async global->LDS, 16 B per lane. LDS dest = wave-uniform base + lane*16.
__device__ __forceinline__ void gld16(void* lds, const void* gptr) {
    __builtin_amdgcn_global_load_lds(
        (const __attribute__((address_space(1))) unsigned int*)gptr,
        (__attribute__((address_space(3))) unsigned int*)lds,
        16, 0, 0);
}

// ---------------------------------------------------------------------------
// Weight/bias conversion.
// ---------------------------------------------------------------------------
__global__ __launch_bounds__(256) void convw(
    const float* __restrict__ Wq, const float* __restrict__ bq,
    const float* __restrict__ Wk, const float* __restrict__ bk,
    const float* __restrict__ Wv, const float* __restrict__ bv,
    const float* __restrict__ Wo,
    u16* __restrict__ Wqkv, float* __restrict__ qkvb, u16* __restrict__ Wob)
{
    const int idx = blockIdx.x * 256 + threadIdx.x;   // 0 .. 1048575
    Wob[idx] = f2bf(Wo[idx]);
    if (idx < 196608) {
        const int row = idx >> 10, k = idx & 1023;
        float v = (row < 64)  ? Wq[row * 1024 + k] * 0.125f
                : (row < 128) ? Wk[(row - 64) * 1024 + k]
                              : Wv[(row - 128) * 1024 + k];
        Wqkv[idx] = f2bf(v);
    }
    if (idx < 192) {
        qkvb[idx] = (idx < 64) ? bq[idx] * 0.125f
                  : (idx < 128) ? bk[idx - 64] : bv[idx - 128];
    }
}

// ---------------------------------------------------------------------------
// Fused QKV projection: qkv[32768][192] = bf16(X fp32) @ Wqkv^T + b.
// 256 blocks x 512 thr (8 waves). Block tile 128x192; wave(wm 0..3, wn 0..1)
// = 32 rows x 96 cols (2 m-frags x 6 n-frags, 24 MFMA/step).
//
// Traffic-minimal staging (the R13 point):
//   A: X tile 128x64 fp32 (32 KB) staged ONCE per step into LDS via 4
//      coalesced gld16/thread. Global source XOR-pre-swizzled
//      (c' = c ^ (row&7) on 16B slots) so fragment ds_read_b128s spread
//      8 lanes/bank-quad (conflict-free b128). LDS linear (rule 21).
//   W: 192x64 tile (24 KB) fragment-ordered via 3 gld16/thread (as R7-R10).
// Per step per thread: 7 VMEM. Double-buffered; VMWAIT(7); 2 barriers/step.
// Per-CU issued bytes: A 512 KB (no wn duplication) + W 384 KB = 896 KB
// (R8: 1792 KB) -> predicted ~40 µs at the ~10 B/cyc/CU ingest ceiling.
// ---------------------------------------------------------------------------
__global__ __launch_bounds__(512) void qkv_gemm(
    const float* __restrict__ X, const u16* __restrict__ W,
    const float* __restrict__ bias, u16* __restrict__ Out)
{
    __shared__ float  Xs[2][8192];    // 32 KB/buf: slot s=row*16+c', 16 B each
    __shared__ short8 Ws[2][1536];    // 24 KB/buf: [(kk2*12+nt)*64 + lane]

    const int tid = threadIdx.x;
    const int lane = tid & 63, wid = tid >> 6;        // 8 waves
    const int q = lane >> 4, r = lane & 15;
    const int wm = wid >> 1, wn = wid & 1;            // wave = 32 rows x 96 cols
    const long m0 = (long)blockIdx.x * 128;

    // W staging pointers: wave covers sections p = wid*3 .. wid*3+2
    const u16* wp[3];
    #pragma unroll
    for (int i = 0; i < 3; ++i) {
        const int p = wid * 3 + i, kk2 = p / 12, nt = p % 12;
        wp[i] = W + (long)(nt * 16 + r) * 1024 + kk2 * 32 + q * 8;
    }

    // A staging pointers: issue i covers slots s = i*512 + wid*64 + lane.
    // row = s>>4 (0..127), c' = s&15, source slot c = c' ^ (row&7).
    const float* pxa[4];
    #pragma unroll
    for (int i = 0; i < 4; ++i) {
        const int s = i * 512 + wid * 64 + lane;
        const int row = s >> 4;
        const int c = (s & 15) ^ (row & 7);
        pxa[i] = X + (m0 + row) * 1024 + c * 4;
    }

#define STAGEA(b, k) do {                                              \
        _Pragma("unroll")                                              \
        for (int i = 0; i < 4; ++i)                                    \
            gld16(&Xs[b][(i * 512 + wid * 64) * 4], pxa[i] + (k) * 64); \
    } while (0)

#define STAGEW(b, k) do {                                              \
        _Pragma("unroll")                                              \
        for (int i = 0; i < 3; ++i)                                    \
            gld16(&Ws[b][(wid * 3 + i) * 64], wp[i] + (k) * 64);       \
    } while (0)

    f32x4 acc[2][6] = {};

    // prologue: stage step 0 into buf 0 (7 VMEM in flight)
    STAGEA(0, 0);
    STAGEW(0, 0);
    MEMFENCE();

    for (int k = 0; k < 16; ++k) {
        const int buf = k & 1;
        if (k < 15) {
            STAGEA(buf ^ 1, k + 1);
            STAGEW(buf ^ 1, k + 1);
            MEMFENCE();
            VMWAIT(7);             // step-k's 7 landed; step-k+1's 7 flying
        } else {
            VMWAIT(0);
        }
        BAR();                     // all waves' stage(k) visible
        MEMFENCE();                // pin ds_reads after barrier#1
        #pragma unroll
        for (int kk2 = 0; kk2 < 2; ++kk2) {
            union { short8 s; unsigned u[4]; } af[2];
            #pragma unroll
            for (int mt = 0; mt < 2; ++mt) {
                const int row = wm * 32 + mt * 16 + r;
                const int c0 = kk2 * 8 + q * 2;
                const float4 f0 = *(const float4*)
                    &Xs[buf][row * 64 + ((c0    ) ^ (row & 7)) * 4];
                const float4 f1 = *(const float4*)
                    &Xs[buf][row * 64 + ((c0 + 1) ^ (row & 7)) * 4];
                af[mt].u[0] = pack_bf2(f0.x, f0.y);
                af[mt].u[1] = pack_bf2(f0.z, f0.w);
                af[mt].u[2] = pack_bf2(f1.x, f1.y);
                af[mt].u[3] = pack_bf2(f1.z, f1.w);
            }
            #pragma unroll
            for (int j = 0; j < 6; ++j) {
                const short8 bf = Ws[buf][(kk2 * 12 + wn * 6 + j) * 64 + lane];
                acc[0][j] = __builtin_amdgcn_mfma_f32_16x16x32_bf16(
                    af[0].s, bf, acc[0][j], 0, 0, 0);
                acc[1][j] = __builtin_amdgcn_mfma_f32_16x16x32_bf16(
                    af[1].s, bf, acc[1][j], 0, 0, 0);
            }
        }
        MEMFENCE();                // pin ds_reads before barrier#2
        BAR();                     // buf may be overwritten next step
    }
#undef STAGEA
#undef STAGEW

    // ---- epilogue: repack via Xs (64 KB >= 128x192x2 = 48 KB; dead after
    // the last step's barrier#2) -> fully coalesced 16B/lane stores ----
    u16* lds0 = (u16*)&Xs[0][0];
    #pragma unroll
    for (int j = 0; j < 6; ++j) {
        const int col = wn * 96 + j * 16 + r;
        const float badd = bias[col];
        #pragma unroll
        for (int mt = 0; mt < 2; ++mt)
            #pragma unroll
            for (int e = 0; e < 4; ++e)
                lds0[(wm * 32 + mt * 16 + q * 4 + e) * 192 + col] =
                    f2bf(acc[mt][j][e] + badd);
    }
    asm volatile("s_waitcnt lgkmcnt(0)" ::: "memory");
    BAR();
    const short8* l8 = (const short8*)lds0;
    u16* ob = Out + m0 * 192;
    #pragma unroll
    for (int s = 0; s < 6; ++s) {
        short8 v = l8[tid + s * 512];
        *(short8*)(ob + (long)(tid + s * 512) * 8) = v;
    }
}

// ---------------------------------------------------------------------------
// V transpose: Vt[bh*64 + d][i] <- qkv[b*8192 + i*16 + h][128 + d]
// ---------------------------------------------------------------------------
__global__ __launch_bounds__(256) void vtrans(
    const u16* __restrict__ qkv, u16* __restrict__ Vt)
{
    __shared__ u16 T[64][68];
    const int bh = blockIdx.x, b = bh >> 4, h = bh & 15;
    const int i0 = blockIdx.y * 64;
    const int tid = threadIdx.x;

    #pragma unroll
    for (int it = 0; it < 2; ++it) {
        const int c = tid + 256 * it;
        const int il = c >> 3, d8 = (c & 7) * 8;
        short8 v = *(const short8*)(qkv +
            ((long)b * 8192 + (long)(i0 + il) * 16 + h) * 192 + 128 + d8);
        #pragma unroll
        for (int j = 0; j < 8; ++j) T[d8 + j][il] = (u16)v[j];
    }
    __syncthreads();
    #pragma unroll
    for (int it = 0; it < 2; ++it) {
        const int c = tid + 256 * it;
        const int dl = c >> 3, i8 = (c & 7) * 8;
        short8 o;
        #pragma unroll
        for (int j = 0; j < 8; ++j) o[j] = (short)T[dl][i8 + j];
        *(short8*)(Vt + ((long)bh * 64 + dl) * 512 + i0 + i8) = o;
    }
}

// ---------------------------------------------------------------------------
// Fused flash attention, S^T formulation. Block = (q-tile of 64, bh); 4
// waves, 16 queries each. K/V chunks (64 keys) double-buffered in LDS via
// global_load_lds, counted-vmcnt two-barrier schedule per chunk.
//   S^T = MFMA(A=K, B=Q): lane(q,r) holds S^T[key=ct*16+q*4+e][query=r]
//   -> softmax over keys = 15 in-lane ops + 2 shuffles (XOR 16,32)
//   P^T packed to LDS as P[query][key] (stride 72, wave-private);
//   O^T = MFMA(A=V^T, B=P): lane holds O^T[d=nt*16+q*4+e][query=r].
// ---------------------------------------------------------------------------
__global__ __launch_bounds__(256) void attn_flash(
    const u16* __restrict__ qkv, const u16* __restrict__ Vt,
    u16* __restrict__ ctx)
{
    __shared__ short8 Ks[2][512];      // [f*256 + ct*64 + q*16 + r]
    __shared__ short8 Vs[2][512];      // [f*256 + nt*64 + q*16 + r]
    __shared__ u16 Plds[4][16 * 72];   // wave-private P[query][key]

    const int tid = threadIdx.x, lane = tid & 63, wid = tid >> 6;
    const int q = lane >> 4, r = lane & 15;
    const int qt = blockIdx.x;         // 0..7
    const int bh = blockIdx.y;         // 0..63
    const int b = bh >> 4, h = bh & 15;
    const long qrowbase = (long)b * 8192 + h;

    // Q B-fragments: lane(q,r) needs Q[query=r][d=q*8+j] (2 d-halves)
    short8 Qf0, Qf1;
    {
        const int i = qt * 64 + wid * 16 + r;
        const u16* p = qkv + (qrowbase + (long)i * 16) * 192 + q * 8;
        Qf0 = *(const short8*)(p);
        Qf1 = *(const short8*)(p + 32);
    }

    // staging pointers (this thread: key/row = wid*16 + r, d-octet q)
    const u16* kbase = qkv + (qrowbase + (long)(wid * 16 + r) * 16) * 192
                           + 64 + q * 8;                 // + key*3072 + f*32
    const u16* vbase = Vt + ((long)bh * 64 + wid * 16 + r) * 512 + q * 8;

    gld16(&Ks[0][wid * 64],       kbase);
    gld16(&Ks[0][256 + wid * 64], kbase + 32);
    gld16(&Vs[0][wid * 64],       vbase);
    gld16(&Vs[0][256 + wid * 64], vbase + 32);
    // no prologue barrier: chunk-0's counted wait + barrier#1 covers it

    f32x4 O[4] = {};
    float mrun = -1e30f, lrun = 0.f;   // per-lane scalars (query = r)
    u16* Pw = &Plds[wid][0];

    for (int c = 0; c < 8; ++c) {
        const int j0 = c * 64, buf = c & 1;
        if (c < 7) {
            const u16* kp = kbase + (long)(j0 + 64) * 3072;
            const u16* vp = vbase + j0 + 64;
            gld16(&Ks[buf ^ 1][wid * 64],       kp);
            gld16(&Ks[buf ^ 1][256 + wid * 64], kp + 32);
            gld16(&Vs[buf ^ 1][wid * 64],       vp);
            gld16(&Vs[buf ^ 1][256 + wid * 64], vp + 32);
            VMWAIT(4);             // chunk-c data landed; c+1 in flight
        } else {
            VMWAIT(0);
        }
        BAR();
        MEMFENCE();
        // ---- S^T chunk: lane holds S^T[key=ct*16+q*4+e][query r] ----
        f32x4 S[4];
        #pragma unroll
        for (int ct = 0; ct < 4; ++ct) {
            f32x4 s = {};
            s = __builtin_amdgcn_mfma_f32_16x16x32_bf16(
                Ks[buf][ct * 64 + lane], Qf0, s, 0, 0, 0);
            s = __builtin_amdgcn_mfma_f32_16x16x32_bf16(
                Ks[buf][256 + ct * 64 + lane], Qf1, s, 0, 0, 0);
            S[ct] = s;
        }
        // ---- online softmax (per query r): in-lane 16 + 2 shuffles ----
        float mc = -1e30f;
        #pragma unroll
        for (int ct = 0; ct < 4; ++ct)
            mc = fmaxf(mc, fmaxf(fmaxf(S[ct][0], S[ct][1]),
                                 fmaxf(S[ct][2], S[ct][3])));
        mc = fmaxf(mc, __shfl_xor(mc, 16, 64));
        mc = fmaxf(mc, __shfl_xor(mc, 32, 64));
        const float mnew = fmaxf(mrun, mc);
        const float alpha = __expf(mrun - mnew);
        mrun = mnew;
        float se = 0.f;
        #pragma unroll
        for (int ct = 0; ct < 4; ++ct)
            #pragma unroll
            for (int e = 0; e < 4; ++e) {
                const float pv = __expf(S[ct][e] - mnew);
                S[ct][e] = pv; se += pv;
            }
        se += __shfl_xor(se, 16, 64);
        se += __shfl_xor(se, 32, 64);
        lrun = lrun * alpha + se;
        #pragma unroll
        for (int nt = 0; nt < 4; ++nt)
            #pragma unroll
            for (int e = 0; e < 4; ++e) O[nt][e] *= alpha;
        // ---- P^T -> LDS as P[query][key], packed b64 writes ----
        #pragma unroll
        for (int ct = 0; ct < 4; ++ct) {
            uint2 d;
            d.x = pack_bf2(S[ct][0], S[ct][1]);
            d.y = pack_bf2(S[ct][2], S[ct][3]);
            *(uint2*)(Pw + r * 72 + ct * 16 + q * 4) = d;
        }
        short8 Pf0 = *(const short8*)(Pw + r * 72 + q * 8);
        short8 Pf1 = *(const short8*)(Pw + r * 72 + 32 + q * 8);
        // ---- O^T += MFMA(A=V^T, B=P) ----
        #pragma unroll
        for (int nt = 0; nt < 4; ++nt) {
            O[nt] = __builtin_amdgcn_mfma_f32_16x16x32_bf16(
                Vs[buf][nt * 64 + lane], Pf0, O[nt], 0, 0, 0);
            O[nt] = __builtin_amdgcn_mfma_f32_16x16x32_bf16(
                Vs[buf][256 + nt * 64 + lane], Pf1, O[nt], 0, 0, 0);
        }
        MEMFENCE();
        BAR();
    }

    // ---- epilogue: normalize, write ctx[b*512+i][h*64+d], 8B stores ----
    const float inv = 1.0f / lrun;
    const long i = qt * 64 + wid * 16 + r;
    u16* po = ctx + ((long)b * 512 + i) * 1024 + h * 64;
    #pragma unroll
    for (int nt = 0; nt < 4; ++nt) {
        uint2 d;
        d.x = pack_bf2(O[nt][0] * inv, O[nt][1] * inv);
        d.y = pack_bf2(O[nt][2] * inv, O[nt][3] * inv);
        *(uint2*)(po + nt * 16 + q * 4) = d;
    }
}

// ---------------------------------------------------------------------------
// Output projection: out[2048][1024] fp32 = ctx @ Wob^T + bo.
// 64x64 tile, BK=64, both operands via global_load_lds, double-buffered,
// counted-vmcnt two-barrier schedule (4 gld16/step in flight).
// ---------------------------------------------------------------------------
__global__ __launch_bounds__(256) void gemm_o(
    const u16* __restrict__ A, const u16* __restrict__ B,
    const float* __restrict__ bias, float* __restrict__ C)
{
    __shared__ short8 As[2][512];   // [f*256 + mt*64 + q*16 + r]
    __shared__ short8 Bs[2][512];

    const int tid = threadIdx.x;
    const int lane = tid & 63, wid = tid >> 6;
    const int q = lane >> 4, r = lane & 15;
    const long m0 = (long)blockIdx.x * 64, n0 = (long)blockIdx.y * 64;
    const int wm = wid >> 1, wn = wid & 1;

    const u16* ap[2];
    const u16* bp[2];
    #pragma unroll
    for (int i = 0; i < 2; ++i) {
        const int t = wid * 2 + i, f = t >> 2, mt = t & 3;
        ap[i] = A + (m0 + mt * 16 + r) * 1024 + f * 32 + q * 8;
        bp[i] = B + (n0 + mt * 16 + r) * 1024 + f * 32 + q * 8;
    }

    #pragma unroll
    for (int i = 0; i < 2; ++i) {
        gld16(&As[0][(wid * 2 + i) * 64], ap[i]);
        gld16(&Bs[0][(wid * 2 + i) * 64], bp[i]);
    }
    // no prologue barrier: step-0's counted wait + barrier#1 covers it

    f32x4 acc[2][2] = {};

    for (int k0 = 0; k0 < 1024; k0 += 64) {
        const int buf = (k0 >> 6) & 1;
        if (k0 + 64 < 1024) {
            #pragma unroll
            for (int i = 0; i < 2; ++i) {
                gld16(&As[buf ^ 1][(wid * 2 + i) * 64], ap[i] + k0 + 64);
                gld16(&Bs[buf ^ 1][(wid * 2 + i) * 64], bp[i] + k0 + 64);
            }
            VMWAIT(4);             // step-i data landed; i+1 in flight
        } else {
            VMWAIT(0);
        }
        BAR();
        MEMFENCE();
        #pragma unroll
        for (int f = 0; f < 2; ++f) {
            short8 af0 = As[buf][f * 256 + (wm * 2 + 0) * 64 + lane];
            short8 af1 = As[buf][f * 256 + (wm * 2 + 1) * 64 + lane];
            short8 bf0 = Bs[buf][f * 256 + (wn * 2 + 0) * 64 + lane];
            short8 bf1 = Bs[buf][f * 256 + (wn * 2 + 1) * 64 + lane];
            acc[0][0] = __builtin_amdgcn_mfma_f32_16x16x32_bf16(af0, bf0, acc[0][0], 0, 0, 0);
            acc[0][1] = __builtin_amdgcn_mfma_f32_16x16x32_bf16(af0, bf1, acc[0][1], 0, 0, 0);
            acc[1][0] = __builtin_amdgcn_mfma_f32_16x16x32_bf16(af1, bf0, acc[1][0], 0, 0, 0);
            acc[1][1] = __builtin_amdgcn_mfma_f32_16x16x32_bf16(af1, bf1, acc[1][1], 0, 0, 0);
        }
        MEMFENCE();
        BAR();
    }

    #pragma unroll
    for (int i = 0; i < 2; ++i)
        #pragma unroll
        for (int j = 0; j < 2; ++j) {
            const long col = n0 + (wn * 2 + j) * 16 + r;
            const float badd = bias[col];
            #pragma unroll
            for (int e = 0; e < 4; ++e) {
                const long row = m0 + (wm * 2 + i) * 16 + q * 4 + e;
                C[row * 1024 + col] = acc[i][j][e] + badd;
            }
        }
}

// ---------------------------------------------------------------------------
extern "C" void kernel_launch(void* const* d_in, const int* in_sizes, int n_in,
                              void* d_out, int out_size, void* d_ws, size_t ws_size,
                              hipStream_t stream)
{
    const float* x  = (const float*)d_in[0];
    const float* Wq = (const float*)d_in[1];
    const float* bq = (const float*)d_in[2];
    const float* Wk = (const float*)d_in[3];
    const float* bk = (const float*)d_in[4];
    const float* Wv = (const float*)d_in[5];
    const float* bv = (const float*)d_in[6];
    const float* Wo = (const float*)d_in[7];
    const float* bo = (const float*)d_in[8];
    float* out = (float*)d_out;
    char* ws = (char*)d_ws;

    u16*   qkv  = (u16*)(ws);                   // 32768*192*2   = 12,582,912
    u16*   Vt   = (u16*)(ws + 12582912);        // 64*64*512*2   =  4,194,304
    u16*   Wqkv = (u16*)(ws + 16777216);        // 192*1024*2    =    393,216
    u16*   Wob  = (u16*)(ws + 17170432);        // 1024*1024*2   =  2,097,152
    float* qkvb = (float*)(ws + 19267584);      // 192*4
    u16*   ctx  = (u16*)(ws + 19268352);        // 2048*1024*2   =  4,194,304

    convw<<<4096, 256, 0, stream>>>(Wq, bq, Wk, bk, Wv, bv, Wo, Wqkv, qkvb, Wob);
    qkv_gemm<<<256, 512, 0, stream>>>(x, Wqkv, qkvb, qkv);
    vtrans<<<dim3(64, 8), 256, 0, stream>>>(qkv, Vt);
    attn_flash<<<dim3(8, 64), 256, 0, stream>>>(qkv, Vt, ctx);
    gemm_o<<<dim3(32, 16), 256, 0, stream>>>(ctx, Wob, bo, out);
}